// Round 1
// 88.447 us; speedup vs baseline: 1.0020x; 1.0020x over previous
//
#include <hip/hip_runtime.h>
#include <stdint.h>

// Problem constants (CLUSTER_AMNT=1024, CLUSTER_SIZE=8, EMBED_DIM=128)
#define N_TOTAL 8192
#define EMBED   128
#define CSIZE   8
#define MARGIN  1.0f
#define BIGF    3.0e38f

// Symmetric tiling: 32x32 grid of 256x256 tiles, compute i<=j only.
#define TILE       256
#define NT         (N_TOTAL / TILE)       // 32
#define NPAIR      (NT * (NT + 1) / 2)    // 528
#define STEP_COLS  32
#define STEPS      (TILE / STEP_COLS)     // 8
#define ROW_BLOCKS NT                     // 32 done-counters

typedef __attribute__((ext_vector_type(8))) short  short8;   // 8 bf16 (4 VGPRs)
typedef __attribute__((ext_vector_type(4))) float  floatx4;  // MFMA C/D

__device__ __forceinline__ unsigned short f2bf(float f) {
    union { float f; unsigned u; } v; v.f = f;
    unsigned u = v.u;
    unsigned r = u + 0x7FFFu + ((u >> 16) & 1u);  // RNE bf16
    return (unsigned short)(r >> 16);
}

__device__ __forceinline__ void gl_lds16(const void* g, void* l) {
    __builtin_amdgcn_global_load_lds(
        (const __attribute__((address_space(1))) void*)g,
        (__attribute__((address_space(3))) void*)l, 16, 0, 0);
}

// ---------------------------------------------------------------------------
// prep_pos: fused. 4 waves/block, one cluster per wave (wave-synchronous).
// fp32->bf16 cast-out, exact fp32 row norms, hard positive, negBits=+inf,
// zero the 32 per-rowBlock done counters and out[0].
// ---------------------------------------------------------------------------
__global__ __launch_bounds__(256) void prep_pos_kernel(
        const float* __restrict__ emb,
        unsigned short* __restrict__ ebf,
        float* __restrict__ n2,
        float* __restrict__ ap,
        unsigned* __restrict__ negBits,
        unsigned* __restrict__ cnt,
        float* __restrict__ out) {
    __shared__ __align__(16) float ls[4][CSIZE][EMBED + 4];  // row stride 132
    int tid  = threadIdx.x;
    int w    = tid >> 6;
    int lane = tid & 63;
    int c    = blockIdx.x * 4 + w;

    const float4* base = (const float4*)(emb + (size_t)c * CSIZE * EMBED);
    float4 v[4];
#pragma unroll
    for (int i = 0; i < 4; ++i) v[i] = base[lane + i * 64];

#pragma unroll
    for (int i = 0; i < 4; ++i) {
        int elem = (lane + i * 64) * 4;
        int r = elem >> 7, k = elem & 127;
        *(float4*)&ls[w][r][k] = v[i];
    }

    ushort4* dst = (ushort4*)(ebf + (size_t)c * CSIZE * EMBED);
#pragma unroll
    for (int i = 0; i < 4; ++i) {
        ushort4 o;
        o.x = f2bf(v[i].x); o.y = f2bf(v[i].y);
        o.z = f2bf(v[i].z); o.w = f2bf(v[i].w);
        dst[lane + i * 64] = o;
    }

    int i8 = lane >> 3, j8 = lane & 7;
    float sq = 0.f, s2 = 0.f;
#pragma unroll 8
    for (int k4 = 0; k4 < EMBED / 4; ++k4) {
        float4 a = *(const float4*)&ls[w][i8][k4 * 4];
        float4 b = *(const float4*)&ls[w][j8][k4 * 4];
        float d0 = a.x - b.x, d1 = a.y - b.y, d2 = a.z - b.z, d3 = a.w - b.w;
        sq = fmaf(d0, d0, sq); sq = fmaf(d1, d1, sq);
        sq = fmaf(d2, d2, sq); sq = fmaf(d3, d3, sq);
        s2 = fmaf(a.x, a.x, s2); s2 = fmaf(a.y, a.y, s2);
        s2 = fmaf(a.z, a.z, s2); s2 = fmaf(a.w, a.w, s2);
    }
#pragma unroll
    for (int off = 1; off < 8; off <<= 1) sq = fmaxf(sq, __shfl_xor(sq, off));
    if (j8 == 0) {
        ap[c * CSIZE + i8] = sqrtf(sq);
        n2[c * CSIZE + i8] = s2;
    }
    if (lane < CSIZE) negBits[c * CSIZE + lane] = 0x7F800000u;  // +inf
    if (blockIdx.x == 0) {
        if (tid < ROW_BLOCKS) cnt[tid] = 0u;
        if (tid == 0) out[0] = 0.f;
    }
}

// ---------------------------------------------------------------------------
// neg: symmetric bf16 MFMA Gram. One block per tile pair (i<=j) of the
// 32x32 grid of 256x256 tiles (528 blocks). Accumulator is initialized to
// -0.5*n2_col - 0.5*n2_row, so acc = G - 0.5*(n2_r + n2_c) and the hard-
// negative min-dist^2 along EITHER axis is -2*max(acc):
//   rows of tile i  <- row-max over the tile's 256 cols (registers)
//   cols (= rows of tile j) <- col-max over the tile's 256 rows (LDS, off-diag)
// Diagonal tiles (i==j) mask same-cluster pairs and need row-max only
// (tile is symmetric). B staged via double-buffered global_load_lds (w=16),
// one barrier per 32-col step; prefetch issued before consuming so the
// pre-barrier vmcnt drain overlaps MFMA. Per-rowBlock done counters (32
// contributors each) trigger the 256-row loss reduction.
// ---------------------------------------------------------------------------
__global__ __launch_bounds__(256, 2) void neg_kernel(
        const unsigned short* __restrict__ ebf,
        const float* __restrict__ n2,
        const float* __restrict__ ap,
        unsigned* __restrict__ negBits,
        unsigned* __restrict__ cnt,
        float* __restrict__ out) {
    __shared__ __align__(16) unsigned char btile[2][STEP_COLS * 256];  // 2 x 8 KB
    __shared__ float n2l[TILE];       // 1 KB: -0.5*n2 of this tile's cols
    __shared__ float cw[4][TILE];     // 4 KB: per-wave col maxes
    __shared__ unsigned finT[2];
    __shared__ int nFin;
    __shared__ float wsum[4];

    int lane = threadIdx.x & 63;
    int w    = threadIdx.x >> 6;
    int quad = lane >> 4;
    int l16  = lane & 15;

    // decode (ti, tj) with ti <= tj from linear pair index
    int t = blockIdx.x, ti = 0;
    while (t >= NT - ti) { t -= NT - ti; ++ti; }
    int tj = ti + t;
    bool isDiag = (ti == tj);

    int rowBase  = ti * TILE;
    int colBase  = tj * TILE;
    int rowStrip = rowBase + w * 64;

    // col-norm tile (scaled -0.5)
    for (int k = threadIdx.x; k < TILE; k += 256)
        n2l[k] = -0.5f * n2[colBase + k];

    // A fragments: 4 row-tiles x 4 K-chunks, 64 VGPRs. A[m=l16][k=quad*8+j+32c]
    short8 afrag[4][4];
#pragma unroll
    for (int rt = 0; rt < 4; ++rt)
#pragma unroll
        for (int c = 0; c < 4; ++c)
            afrag[rt][c] = *(const short8*)(ebf +
                (size_t)(rowStrip + rt * 16 + l16) * EMBED + c * 32 + quad * 8);

    // row half-norms for the 16 rows this lane's acc elements touch
    float rh[4][4];
#pragma unroll
    for (int rt = 0; rt < 4; ++rt)
#pragma unroll
        for (int r = 0; r < 4; ++r)
            rh[rt][r] = 0.5f * n2[rowStrip + rt * 16 + quad * 4 + r];

    float mx[4][4];  // running row-side max of (G - 0.5*n2_c - 0.5*n2_r)
#pragma unroll
    for (int rt = 0; rt < 4; ++rt)
#pragma unroll
        for (int r = 0; r < 4; ++r) mx[rt][r] = -BIGF;

    // staging geometry (per wave: 2 insts; si = w*2+i covers cols 4si..4si+3)
    const char* gbase = (const char*)ebf;
    int jl[2], chn[2];
#pragma unroll
    for (int i = 0; i < 2; ++i) {
        int si = w * 2 + i;
        jl[i]  = 4 * si + (lane >> 4);           // 0..31 local col
        chn[i] = (lane & 15) ^ (jl[i] & 15);     // xor-swizzled 16B chunk
    }

    // prime buffer 0
#pragma unroll
    for (int i = 0; i < 2; ++i) {
        int si = w * 2 + i;
        const char* gp = gbase + ((size_t)(colBase + jl[i]) << 8) + (chn[i] << 4);
        gl_lds16(gp, (char*)btile[0] + (si << 10));
    }
    __syncthreads();  // buffer 0 staged, n2l ready

#pragma unroll 1
    for (int s = 0; s < STEPS; ++s) {
        int cur = s & 1;
        if (s < STEPS - 1) {  // prefetch s+1 into the other buffer
#pragma unroll
            for (int i = 0; i < 2; ++i) {
                int si = w * 2 + i;
                const char* gp = gbase +
                    ((size_t)(colBase + (s + 1) * STEP_COLS + jl[i]) << 8) + (chn[i] << 4);
                gl_lds16(gp, (char*)btile[cur ^ 1] + (si << 10));
            }
        }
        float nhalf0 = n2l[s * STEP_COLS + l16];
        float nhalf1 = n2l[s * STEP_COLS + 16 + l16];

#pragma unroll
        for (int h = 0; h < 2; ++h) {
            float nh = h ? nhalf1 : nhalf0;
            short8 bfrag[4];
#pragma unroll
            for (int c = 0; c < 4; ++c)
                bfrag[c] = *(const short8*)((const unsigned char*)btile[cur] +
                    (((h * 16 + l16) << 8) | ((((c << 2) + quad) ^ l16) << 4)));
            int colB = colBase + s * STEP_COLS + h * 16;
            float cm = -BIGF;  // this (step,half)'s col max over 16 own rows
#pragma unroll
            for (int rt = 0; rt < 4; ++rt) {
                floatx4 acc = {nh - rh[rt][0], nh - rh[rt][1],
                               nh - rh[rt][2], nh - rh[rt][3]};
#pragma unroll
                for (int c = 0; c < 4; ++c)
                    acc = __builtin_amdgcn_mfma_f32_16x16x32_bf16(
                        afrag[rt][c], bfrag[c], acc, 0, 0, 0);
                if (isDiag && colB == rowStrip + rt * 16) {  // wave-uniform
                    bool skip = ((quad >> 1) == (l16 >> 3));  // same 8-cluster
#pragma unroll
                    for (int r = 0; r < 4; ++r) {
                        float v = skip ? -BIGF : acc[r];
                        mx[rt][r] = fmaxf(mx[rt][r], v);
                    }
                } else {
#pragma unroll
                    for (int r = 0; r < 4; ++r) {
                        float v = acc[r];
                        mx[rt][r] = fmaxf(mx[rt][r], v);
                        cm = fmaxf(cm, v);
                    }
                }
            }
            if (!isDiag) {  // fold quads -> full 64 rows, park in LDS
                float v = fmaxf(cm, __shfl_xor(cm, 16));
                v = fmaxf(v, __shfl_xor(v, 32));
                if (quad == 0) cw[w][s * STEP_COLS + h * 16 + l16] = v;
            }
        }
        __syncthreads();  // readers of btile[cur] done; stage(s+1) drained
    }

    // ---- row-side commit: reduce over 16 col-lanes, atomicMin per row
#pragma unroll
    for (int rt = 0; rt < 4; ++rt) {
#pragma unroll
        for (int r = 0; r < 4; ++r) {
            float m = mx[rt][r];
#pragma unroll
            for (int off = 1; off < 16; off <<= 1)
                m = fmaxf(m, __shfl_xor(m, off));
            if (l16 == 0) {
                int row = rowStrip + rt * 16 + quad * 4 + r;
                float val = fmaxf(-2.f * m, 0.f);  // n2r + n2c - 2G
                atomicMin(&negBits[row], __float_as_uint(val));
            }
        }
    }

    // ---- col-side commit (off-diagonal only): combine 4 waves, one per col
    if (!isDiag) {
        int c = threadIdx.x;
        float m0 = fmaxf(cw[0][c], cw[1][c]);
        float m1 = fmaxf(cw[2][c], cw[3][c]);
        float val = fmaxf(-2.f * fmaxf(m0, m1), 0.f);
        atomicMin(&negBits[colBase + c], __float_as_uint(val));
    }

    // ---- per-rowBlock finalize: 32 contributors each; last one reduces
    __syncthreads();
    if (threadIdx.x == 0) {
        __threadfence();
        int n = 0;
        if (atomicAdd(&cnt[ti], 1u) == NT - 1) finT[n++] = (unsigned)ti;
        if (!isDiag && atomicAdd(&cnt[tj], 1u) == NT - 1) finT[n++] = (unsigned)tj;
        nFin = n;
    }
    __syncthreads();
    for (int f = 0; f < nFin; ++f) {
        int rb  = (int)finT[f];
        int row = rb * 256 + threadIdx.x;
        unsigned u = atomicOr(&negBits[row], 0u);  // device-coherent read
        float an = sqrtf(__uint_as_float(u));
        float sres = fmaxf(ap[row] - an + MARGIN, 0.f);
#pragma unroll
        for (int off = 1; off < 64; off <<= 1) sres += __shfl_xor(sres, off);
        if (lane == 0) wsum[w] = sres;
        __syncthreads();
        if (threadIdx.x == 0)
            atomicAdd(out, (wsum[0] + wsum[1] + wsum[2] + wsum[3]) * (1.0f / N_TOTAL));
        __syncthreads();
    }
}

extern "C" void kernel_launch(void* const* d_in, const int* in_sizes, int n_in,
                              void* d_out, int out_size, void* d_ws, size_t ws_size,
                              hipStream_t stream) {
    const float* emb = (const float*)d_in[0];
    float* out = (float*)d_out;

    char* ws = (char*)d_ws;
    unsigned short* ebf     = (unsigned short*)ws;                          // 2 MiB
    float*          n2      = (float*)(ws + 2 * 1024 * 1024);               // 32 KiB
    float*          ap      = (float*)(ws + 2 * 1024 * 1024 + 32 * 1024);   // 32 KiB
    unsigned*       negBits = (unsigned*)(ws + 2 * 1024 * 1024 + 64 * 1024);// 32 KiB
    unsigned*       cnt     = (unsigned*)(ws + 2 * 1024 * 1024 + 96 * 1024);

    prep_pos_kernel<<<N_TOTAL / CSIZE / 4, 256, 0, stream>>>(emb, ebf, n2, ap, negBits, cnt, out);
    neg_kernel<<<NPAIR, 256, 0, stream>>>(ebf, n2, ap, negBits, cnt, out);
}